// Round 3
// baseline (4999.250 us; speedup 1.0000x reference)
//
#include <hip/hip_runtime.h>

#define HH 128
#define WW 128

typedef float f32x4 __attribute__((ext_vector_type(4)));
typedef float f32x8 __attribute__((ext_vector_type(8)));

__device__ __forceinline__ float hsig(float x) {
    return fminf(fmaxf(fmaf(0.2f, x, 0.5f), 0.f), 1.f);
}

constexpr int ST = 125;   // channel-plane stride in LDS (words); 125 mod 32 = 29

// Software-pipelined conv accumulation over N input channels for one tap.
// Weights: uniform addresses -> s_load_dwordx8 (SGPR broadcast, prefetched 1 ci
// ahead). Activations: per-lane ds_read_b32, prefetched 2 ci ahead (DS latency
// ~120cyc > one 64cyc FMA burst). The lgkmcnt waits land AFTER the FMA burst.
template<int N>
__device__ __forceinline__ void conv_accum(const float* __restrict__ wbase,
                                           const float* sp,
                                           float acc[4][8])
{
    f32x8 w0 = *(const f32x8*)(wbase);
    f32x8 w1 = *(const f32x8*)(wbase + 32);
    f32x8 w2 = *(const f32x8*)(wbase + 64);
    f32x8 w3 = *(const f32x8*)(wbase + 96);
    float a0 = sp[0];
    float a1 = sp[ST];
    #pragma unroll 1
    for (int ci = 0; ci < N; ++ci) {
        const int cn = (ci + 1 < N) ? ci + 1 : N - 1;   // clamp (uniform s_cselect)
        const float* wb = wbase + cn * 128;
        const f32x8 n0 = *(const f32x8*)(wb);
        const f32x8 n1 = *(const f32x8*)(wb + 32);
        const f32x8 n2 = *(const f32x8*)(wb + 64);
        const f32x8 n3 = *(const f32x8*)(wb + 96);
        const int c2 = (ci + 2 < N) ? ci + 2 : N - 1;
        const float a2 = sp[c2 * ST];
        #pragma unroll
        for (int j = 0; j < 8; ++j) acc[0][j] = fmaf(a0, w0[j], acc[0][j]);
        #pragma unroll
        for (int j = 0; j < 8; ++j) acc[1][j] = fmaf(a0, w1[j], acc[1][j]);
        #pragma unroll
        for (int j = 0; j < 8; ++j) acc[2][j] = fmaf(a0, w2[j], acc[2][j]);
        #pragma unroll
        for (int j = 0; j < 8; ++j) acc[3][j] = fmaf(a0, w3[j], acc[3][j]);
        a0 = a1; a1 = a2;
        w0 = n0; w1 = n1; w2 = n2; w3 = n3;
    }
}

// One ConvLSTM step, one layer. Block = 8x8 pixel tile x batch; wave = filter
// group (8 filters, all 4 gates); lane = pixel. One barrier per kernel.
// Tap order rotated per (block, wave) to de-lockstep co-resident waves.
template<int CIN>
__global__ __launch_bounds__(256)
void lstm_step(const float* __restrict__ xin, size_t xbs,
               const float* __restrict__ res,
               const float* __restrict__ Wx,
               const float* __restrict__ Wh,
               const float* __restrict__ bias,
               const float* __restrict__ hprev,
               float* __restrict__ cst,
               float* __restrict__ hout,
               const int mode)   // 0 raw, 1 relu(x), 2 relu(x+res)
{
    __shared__ float sact[(CIN + 32) * ST];   // x planes [0,CIN), h planes [CIN,CIN+32)

    const int tid = threadIdx.x;
    const int bx = blockIdx.x, by = blockIdx.y, bb = blockIdx.z;
    const int x0 = bx * 8 - 1, y0 = by * 8 - 1;   // halo origin

    // ---- stage x halo tile (10x10), float4 loads, transpose to [ci][pix] ----
    for (int i = tid; i < 100 * (CIN / 4); i += 256) {
        const int pix = i / (CIN / 4);
        const int c4  = i - pix * (CIN / 4);
        const int ry = pix / 10, rx = pix - ry * 10;
        const int gy = y0 + ry, gx = x0 + rx;
        f32x4 v = {0.f, 0.f, 0.f, 0.f};
        if ((unsigned)gy < HH && (unsigned)gx < WW) {
            v = *(const f32x4*)(xin + (size_t)bb * xbs + ((size_t)gy * WW + gx) * CIN + c4 * 4);
            if (mode == 2) {
                f32x4 r = *(const f32x4*)(res + (((size_t)bb * HH + gy) * WW + gx) * 32 + c4 * 4);
                v.x += r.x; v.y += r.y; v.z += r.z; v.w += r.w;
            }
            if (mode != 0) {
                v.x = fmaxf(v.x, 0.f); v.y = fmaxf(v.y, 0.f);
                v.z = fmaxf(v.z, 0.f); v.w = fmaxf(v.w, 0.f);
            }
        }
        const int off = ry * 12 + rx;
        sact[(c4 * 4 + 0) * ST + off] = v.x;
        sact[(c4 * 4 + 1) * ST + off] = v.y;
        sact[(c4 * 4 + 2) * ST + off] = v.z;
        sact[(c4 * 4 + 3) * ST + off] = v.w;
    }
    // ---- stage hprev halo tile ----
    for (int i = tid; i < 100 * 8; i += 256) {
        const int pix = i >> 3;
        const int c4  = i & 7;
        const int ry = pix / 10, rx = pix - ry * 10;
        const int gy = y0 + ry, gx = x0 + rx;
        f32x4 v = {0.f, 0.f, 0.f, 0.f};
        if ((unsigned)gy < HH && (unsigned)gx < WW)
            v = *(const f32x4*)(hprev + (((size_t)bb * HH + gy) * WW + gx) * 32 + c4 * 4);
        const int off = ry * 12 + rx;
        sact[(CIN + c4 * 4 + 0) * ST + off] = v.x;
        sact[(CIN + c4 * 4 + 1) * ST + off] = v.y;
        sact[(CIN + c4 * 4 + 2) * ST + off] = v.z;
        sact[(CIN + c4 * 4 + 3) * ST + off] = v.w;
    }
    __syncthreads();   // the only barrier

    const int lane = tid & 63;
    const int cg   = tid >> 6;
    const int cg8  = __builtin_amdgcn_readfirstlane(cg * 8);
    const int py = lane >> 3, px = lane & 7;

    float acc[4][8];   // [gate i,f,g,o][filter]
    #pragma unroll
    for (int g = 0; g < 4; ++g) {
        const f32x8 b = *(const f32x8*)(bias + g * 32 + cg8);
        #pragma unroll
        for (int j = 0; j < 8; ++j) acc[g][j] = b[j];
    }

    // de-lockstep: each (block, wave) walks the 9 taps in a rotated order
    const int rot = __builtin_amdgcn_readfirstlane((bx * 2 + by * 5 + cg) % 9);

    #pragma unroll 1
    for (int tp = 0; tp < 9; ++tp) {
        int tap = tp + rot; if (tap >= 9) tap -= 9;
        const int dy = tap / 3, dx = tap - dy * 3;
        const int lp = (py + dy) * 12 + (px + dx);
        conv_accum<CIN>(Wx + (size_t)tap * CIN * 128 + cg8, sact + lp, acc);
        conv_accum<32> (Wh + (size_t)tap * 32  * 128 + cg8, sact + CIN * ST + lp, acc);
    }

    // ---- gates + state update ----
    const int gy = by * 8 + py, gx = bx * 8 + px;
    const size_t base = (((size_t)bb * HH + gy) * WW + gx) * 32 + cg8;
    const f32x4 c0 = *(const f32x4*)(cst + base);
    const f32x4 c1 = *(const f32x4*)(cst + base + 4);
    const float cold[8] = {c0.x, c0.y, c0.z, c0.w, c1.x, c1.y, c1.z, c1.w};
    float cn[8], hn[8];
    #pragma unroll
    for (int j = 0; j < 8; ++j) {
        const float ig = hsig(acc[0][j]);
        const float fg = hsig(acc[1][j]);
        const float gg = tanhf(acc[2][j]);
        const float og = hsig(acc[3][j]);
        const float c2 = fmaf(fg, cold[j], ig * gg);
        cn[j] = c2;
        hn[j] = og * tanhf(c2);
    }
    *(f32x4*)(cst + base)     = (f32x4){cn[0], cn[1], cn[2], cn[3]};
    *(f32x4*)(cst + base + 4) = (f32x4){cn[4], cn[5], cn[6], cn[7]};
    *(f32x4*)(hout + base)     = (f32x4){hn[0], hn[1], hn[2], hn[3]};
    *(f32x4*)(hout + base + 4) = (f32x4){hn[4], hn[5], hn[6], hn[7]};
}

extern "C" void kernel_launch(void* const* d_in, const int* in_sizes, int n_in,
                              void* d_out, int out_size, void* d_ws, size_t ws_size,
                              hipStream_t stream) {
    const float* x = (const float*)d_in[0];
    const float* Wx[4] = {(const float*)d_in[1], (const float*)d_in[4],
                          (const float*)d_in[7], (const float*)d_in[10]};
    const float* Wh[4] = {(const float*)d_in[2], (const float*)d_in[5],
                          (const float*)d_in[8], (const float*)d_in[11]};
    const float* bs[4] = {(const float*)d_in[3], (const float*)d_in[6],
                          (const float*)d_in[9], (const float*)d_in[12]};
    float* out = (float*)d_out;

    const size_t S  = (size_t)4 * HH * WW * 32;   // one [B,H,W,32] buffer (elements)
    const size_t HB = (size_t)HH * WW * 32;       // per-batch stride of h buffers

    float* ws = (float*)d_ws;
    float* hA[4]; float* hB[4]; float* cs[4];
    for (int l = 0; l < 4; ++l) {
        hA[l] = ws + (size_t)(3 * l + 0) * S;
        hB[l] = ws + (size_t)(3 * l + 1) * S;
        cs[l] = ws + (size_t)(3 * l + 2) * S;
    }
    for (int l = 0; l < 4; ++l) {
        hipMemsetAsync(hA[l], 0, S * sizeof(float), stream);
        hipMemsetAsync(cs[l], 0, S * sizeof(float), stream);
    }

    dim3 grid(WW / 8, HH / 8, 4);
    dim3 blk(256);

    float* hp[4] = {hA[0], hA[1], hA[2], hA[3]};
    float* hc[4] = {hB[0], hB[1], hB[2], hB[3]};

    for (int t = 0; t < 8; ++t) {
        lstm_step<16><<<grid, blk, 0, stream>>>(
            x + (size_t)t * HH * WW * 16, (size_t)8 * HH * WW * 16, nullptr,
            Wx[0], Wh[0], bs[0], hp[0], cs[0], hc[0], 0);
        lstm_step<32><<<grid, blk, 0, stream>>>(
            hc[0], HB, nullptr,
            Wx[1], Wh[1], bs[1], hp[1], cs[1], hc[1], 0);
        lstm_step<32><<<grid, blk, 0, stream>>>(
            hc[1], HB, nullptr,
            Wx[2], Wh[2], bs[2], hp[2], cs[2], hc[2], 1);
        lstm_step<32><<<grid, blk, 0, stream>>>(
            hc[2], HB, hc[0],
            Wx[3], Wh[3], bs[3], hp[3], cs[3], (t == 7) ? out : hc[3], 2);

        for (int l = 0; l < 4; ++l) { float* tmp = hp[l]; hp[l] = hc[l]; hc[l] = tmp; }
    }
}

// Round 4
// 1467.735 us; speedup vs baseline: 3.4061x; 3.4061x over previous
//
#include <hip/hip_runtime.h>

#define HH 128
#define WW 128

typedef __bf16 bf16;
typedef bf16 bf16x8 __attribute__((ext_vector_type(8)));
typedef float f32x4 __attribute__((ext_vector_type(4)));

__device__ __forceinline__ float hsig(float x) {
    return fminf(fmaxf(fmaf(0.2f, x, 0.5f), 0.f), 1.f);
}

// ---- one-time weight prep: fp32 [tap][ci][cout] -> bf16 Wt[l][tap][cout][ci64]
// ci64: x cins at [0,CX), h cins at [CX,CX+32), zero pad to 64. (CX=16 for l=0)
__global__ void prep_weights(const float* __restrict__ Wx0, const float* __restrict__ Wh0,
                             const float* __restrict__ Wx1, const float* __restrict__ Wh1,
                             const float* __restrict__ Wx2, const float* __restrict__ Wh2,
                             const float* __restrict__ Wx3, const float* __restrict__ Wh3,
                             bf16* __restrict__ Wt)
{
    int idx = blockIdx.x * 256 + threadIdx.x;      // 4*9*128*64 = 294912
    if (idx >= 4 * 9 * 128 * 64) return;
    const int l = idx / 73728;
    int r = idx - l * 73728;
    const int tap = r / (128 * 64);
    r -= tap * 128 * 64;
    const int co = r >> 6;
    const int ci = r & 63;
    const int CX = (l == 0) ? 16 : 32;
    const float* Wx = (l == 0) ? Wx0 : (l == 1) ? Wx1 : (l == 2) ? Wx2 : Wx3;
    const float* Wh = (l == 0) ? Wh0 : (l == 1) ? Wh1 : (l == 2) ? Wh2 : Wh3;
    float v = 0.f;
    if (ci < CX)           v = Wx[((size_t)tap * CX + ci) * 128 + co];
    else if (ci < CX + 32) v = Wh[((size_t)tap * 32 + (ci - CX)) * 128 + co];
    Wt[(size_t)l * 73728 + ((size_t)tap * 128 + co) * 64 + ci] = (bf16)v;
}

// One ConvLSTM step via implicit-GEMM MFMA.
// Block: 16(w) x 8(h) pixel tile x batch. Wave wv owns rows 2wv, 2wv+1.
// A = act[x-row(16)][ci(K=64/tap)], B = Wt[tap][cout][ci], C[x][cout(128)].
// mode: 0 raw, 1 relu(x), 2 relu(x+res). XF32: x input is fp32 (layer 0).
template<int CINX, bool XF32>
__global__ __launch_bounds__(256, 2)
void lstm_step(const void* __restrict__ xin_, size_t xbs,
               const bf16* __restrict__ res,
               const bf16* __restrict__ Wt,
               const float* __restrict__ bias,
               const bf16* __restrict__ hprev,
               float* __restrict__ cst,
               bf16* __restrict__ hout,
               float* __restrict__ outf,
               const int mode)
{
    constexpr int ST = 72;                 // ci stride (elems): 144B -> benign LDS banking
    __shared__ bf16 sact[180 * ST];        // halo 10y x 18x pixels, 64 ci each

    const int tid = threadIdx.x;
    const int bx = blockIdx.x, by = blockIdx.y, bb = blockIdx.z;

    // ---- stage halo (zeros OOB / pad), bf16, [pix][ci] ----
    for (int i = tid; i < 180 * 8; i += 256) {
        const int pix = i >> 3, g = i & 7;           // g: 8-ci chunk
        const int hy = pix / 18, hx = pix - hy * 18;
        const int gy = by * 8 - 1 + hy, gx = bx * 16 - 1 + hx;
        const bool inb = ((unsigned)gy < HH) && ((unsigned)gx < WW);
        float v[8];
        #pragma unroll
        for (int j = 0; j < 8; ++j) v[j] = 0.f;
        if (inb) {
            const size_t poff = (size_t)gy * WW + gx;
            if (g * 8 < CINX) {                       // x part
                if constexpr (XF32) {
                    const float* xp = (const float*)xin_ + (size_t)bb * xbs + poff * CINX + g * 8;
                    const f32x4 a = *(const f32x4*)xp;
                    const f32x4 b = *(const f32x4*)(xp + 4);
                    v[0] = a.x; v[1] = a.y; v[2] = a.z; v[3] = a.w;
                    v[4] = b.x; v[5] = b.y; v[6] = b.z; v[7] = b.w;
                } else {
                    const bf16* xp = (const bf16*)xin_ + (size_t)bb * xbs + poff * CINX + g * 8;
                    const bf16x8 a = *(const bf16x8*)xp;
                    #pragma unroll
                    for (int j = 0; j < 8; ++j) v[j] = (float)a[j];
                    if (mode == 2) {
                        const bf16x8 rr = *(const bf16x8*)(res + ((size_t)bb * HH * WW + poff) * 32 + g * 8);
                        #pragma unroll
                        for (int j = 0; j < 8; ++j) v[j] += (float)rr[j];
                    }
                    if (mode != 0) {
                        #pragma unroll
                        for (int j = 0; j < 8; ++j) v[j] = fmaxf(v[j], 0.f);
                    }
                }
            } else if (g * 8 < CINX + 32) {           // h part
                const bf16* hp = hprev + ((size_t)bb * HH * WW + poff) * 32 + (g * 8 - CINX);
                const bf16x8 a = *(const bf16x8*)hp;
                #pragma unroll
                for (int j = 0; j < 8; ++j) v[j] = (float)a[j];
            }
        }
        bf16x8 w;
        #pragma unroll
        for (int j = 0; j < 8; ++j) w[j] = (bf16)v[j];
        *(bf16x8*)(&sact[pix * ST + g * 8]) = w;
    }
    __syncthreads();

    const int lane = tid & 63;
    const int wv   = tid >> 6;        // wave id: rows 2wv, 2wv+1
    const int col  = lane & 15;       // A row (x) / C col (cout%16) / B col
    const int krow = lane >> 4;       // k-slice

    f32x4 acc[2][8];
    #pragma unroll
    for (int nb = 0; nb < 8; ++nb) {
        const float bv = bias[nb * 16 + col];
        acc[0][nb] = (f32x4){bv, bv, bv, bv};
        acc[1][nb] = (f32x4){bv, bv, bv, bv};
    }

    const bf16* __restrict__ wb0 = Wt + (size_t)col * 64 + krow * 8;

    #pragma unroll 1
    for (int tap = 0; tap < 9; ++tap) {
        const int dy = tap / 3, dx = tap - dy * 3;
        const int r0 = (2 * wv + dy) * 18 + col + dx;
        bf16x8 A[2][2];
        A[0][0] = *(const bf16x8*)(&sact[r0 * ST + krow * 8]);
        A[0][1] = *(const bf16x8*)(&sact[r0 * ST + 32 + krow * 8]);
        A[1][0] = *(const bf16x8*)(&sact[(r0 + 18) * ST + krow * 8]);
        A[1][1] = *(const bf16x8*)(&sact[(r0 + 18) * ST + 32 + krow * 8]);
        const bf16* wt = wb0 + (size_t)tap * 128 * 64;
        bf16x8 Bf[2][8];
        #pragma unroll
        for (int nb = 0; nb < 8; ++nb) {
            Bf[0][nb] = *(const bf16x8*)(wt + (size_t)nb * 16 * 64);
            Bf[1][nb] = *(const bf16x8*)(wt + (size_t)nb * 16 * 64 + 32);
        }
        #pragma unroll
        for (int mt = 0; mt < 2; ++mt)
            #pragma unroll
            for (int kb = 0; kb < 2; ++kb)
                #pragma unroll
                for (int nb = 0; nb < 8; ++nb)
                    acc[mt][nb] = __builtin_amdgcn_mfma_f32_16x16x32_bf16(
                        A[mt][kb], Bf[kb][nb], acc[mt][nb], 0, 0, 0);
    }

    // ---- lane-local LSTM pointwise ----
    // z(y = by*8+2wv+mt, x = bx*16+krow*4+j, cout = nb*16+col); gate=cout/32, filter=cout%32
    #pragma unroll
    for (int mt = 0; mt < 2; ++mt) {
        const int gy = by * 8 + 2 * wv + mt;
        #pragma unroll
        for (int j = 0; j < 4; ++j) {
            const int gx = bx * 16 + krow * 4 + j;
            const size_t pb = (((size_t)bb * HH + gy) * WW + gx) * 32;
            #pragma unroll
            for (int h2 = 0; h2 < 2; ++h2) {
                const int f = h2 * 16 + col;
                const float zi = acc[mt][0 + h2][j];
                const float zf = acc[mt][2 + h2][j];
                const float zg = acc[mt][4 + h2][j];
                const float zo = acc[mt][6 + h2][j];
                const float cold = cst[pb + f];
                const float ig = hsig(zi), fg = hsig(zf);
                const float gg = tanhf(zg), og = hsig(zo);
                const float cn = fmaf(fg, cold, ig * gg);
                cst[pb + f] = cn;
                const float hn = og * tanhf(cn);
                if (outf) outf[pb + f] = hn;
                else      hout[pb + f] = (bf16)hn;
            }
        }
    }
}

extern "C" void kernel_launch(void* const* d_in, const int* in_sizes, int n_in,
                              void* d_out, int out_size, void* d_ws, size_t ws_size,
                              hipStream_t stream) {
    const float* x = (const float*)d_in[0];
    const float* Wx[4] = {(const float*)d_in[1], (const float*)d_in[4],
                          (const float*)d_in[7], (const float*)d_in[10]};
    const float* Wh[4] = {(const float*)d_in[2], (const float*)d_in[5],
                          (const float*)d_in[8], (const float*)d_in[11]};
    const float* bs[4] = {(const float*)d_in[3], (const float*)d_in[6],
                          (const float*)d_in[9], (const float*)d_in[12]};
    float* out = (float*)d_out;

    const size_t S  = (size_t)4 * HH * WW * 32;   // one [B,H,W,32] buffer (elements)
    const size_t HB = (size_t)HH * WW * 32;       // per-batch stride (elements)
    const size_t WT = (size_t)4 * 73728;          // transposed weights (bf16 elems)

    bf16* wt  = (bf16*)d_ws;
    bf16* hb  = wt + WT;
    float* cb = (float*)(hb + 8 * S);
    bf16 *hA[4], *hB[4]; float* cs[4];
    for (int l = 0; l < 4; ++l) {
        hA[l] = hb + (size_t)(2 * l + 0) * S;
        hB[l] = hb + (size_t)(2 * l + 1) * S;
        cs[l] = cb + (size_t)l * S;
    }
    for (int l = 0; l < 4; ++l) {
        hipMemsetAsync(hA[l], 0, S * sizeof(bf16), stream);
        hipMemsetAsync(cs[l], 0, S * sizeof(float), stream);
    }

    prep_weights<<<1152, 256, 0, stream>>>(Wx[0], Wh[0], Wx[1], Wh[1],
                                           Wx[2], Wh[2], Wx[3], Wh[3], wt);

    dim3 grid(WW / 16, HH / 8, 4);
    dim3 blk(256);

    bf16* hp[4] = {hA[0], hA[1], hA[2], hA[3]};
    bf16* hc[4] = {hB[0], hB[1], hB[2], hB[3]};

    for (int t = 0; t < 8; ++t) {
        lstm_step<16, true><<<grid, blk, 0, stream>>>(
            x + (size_t)t * HH * WW * 16, (size_t)8 * HH * WW * 16, nullptr,
            wt + 0 * 73728, bs[0], hp[0], cs[0], hc[0], nullptr, 0);
        lstm_step<32, false><<<grid, blk, 0, stream>>>(
            hc[0], HB, nullptr,
            wt + 1 * 73728, bs[1], hp[1], cs[1], hc[1], nullptr, 0);
        lstm_step<32, false><<<grid, blk, 0, stream>>>(
            hc[1], HB, nullptr,
            wt + 2 * 73728, bs[2], hp[2], cs[2], hc[2], nullptr, 1);
        lstm_step<32, false><<<grid, blk, 0, stream>>>(
            hc[2], HB, hc[0],
            wt + 3 * 73728, bs[3], hp[3], cs[3], hc[3], (t == 7) ? out : nullptr, 2);

        for (int l = 0; l < 4; ++l) { bf16* tmp = hp[l]; hp[l] = hc[l]; hc[l] = tmp; }
    }
}